// Round 8
// baseline (4352.626 us; speedup 1.0000x reference)
//
#include <hip/hip_runtime.h>
#include <hip/hip_bf16.h>
#include <stdint.h>

// ---------- types ----------
using f32x4  = __attribute__((ext_vector_type(4))) float;
using bf16x8 = __attribute__((ext_vector_type(8))) __bf16;
using short8 = __attribute__((ext_vector_type(8))) short;

__device__ __forceinline__ short f2b(float f) {
    unsigned u = __builtin_bit_cast(unsigned, f);
    unsigned r = (u + 0x7fff + ((u >> 16) & 1)) >> 16;   // RNE
    return (short)r;
}
__device__ __forceinline__ float b2f(short s) {
    unsigned u = ((unsigned)(unsigned short)s) << 16;
    return __builtin_bit_cast(float, u);
}
__device__ __forceinline__ float sigf(float x) {
    return __builtin_amdgcn_rcpf(1.f + __expf(-x));
}
__device__ __forceinline__ float tanhf_fast(float x) {
    x = fminf(fmaxf(x, -15.f), 15.f);
    return 2.f * __builtin_amdgcn_rcpf(1.f + __expf(-2.f * x)) - 1.f;
}

// ---------- laneGate ----------
__global__ __launch_bounds__(256) void lanec_k(const float* lane, const float* W1, const float* b1,
                                               const float* W2, const float* b2, float* laneC) {
    int s = blockIdx.x * 256 + threadIdx.x;
    float v = lane[s];
    float acc = b2[0];
    #pragma unroll
    for (int k = 0; k < 32; ++k) {
        float t = fmaxf(v * W1[k] + b1[k], 0.f);
        acc += t * W2[k];
    }
    laneC[s] = 1.f / (1.f + __expf(-acc));
}

// ---------- weight packing ----------
// pW3: MFMA-frag-major for 4-wave layout: [12 kc][4 w][16 f][64 lane][8 e].
// f = g*4 + js (g = gate, js = j-16-slice). (w,js,lj) -> j = 64w + 16js + lj.
// Combined row n = g*256 + j. k = kc*32 + lk*8 + e (k<128 -> Wih, else Whh col k-128).
__global__ __launch_bounds__(256) void pack_k(const float* Wih, const float* Whh, const float* bih,
                                              const float* bhh, const float* oW, const float* fW1,
                                              const float* fW2, const float* eW2,
                                              short* pW3, float* biasP,
                                              short* oWp, short* fW1p, short* fW2p, short* eW2p) {
    int i = blockIdx.x * 256 + threadIdx.x;
    if (i < 393216) {
        int e = i & 7, l = (i >> 3) & 63, f = (i >> 9) & 15, w = (i >> 13) & 3, kc = i >> 15;
        int lj = l & 15, lk = l >> 4;
        int g = f >> 2, js = f & 3;
        int j = 64 * w + 16 * js + lj;
        int n = g * 256 + j;
        int k = kc * 32 + lk * 8 + e;
        pW3[i] = f2b(k < 128 ? Wih[n * 128 + k] : Whh[n * 256 + (k - 128)]);
        return;
    }
    i -= 393216;
    if (i < 1024) {                                    // biasP[w*256 + f*16 + lj]
        int lj = i & 15, f = (i >> 4) & 15, w = i >> 8;
        int g = f >> 2, js = f & 3;
        int j = 64 * w + 16 * js + lj;
        int n = g * 256 + j;
        biasP[i] = bih[n] + bhh[n];
        return;
    }
    i -= 1024;
    if (i < 32768) { oWp[i] = f2b(oW[i]); return; }    // [128][256]
    i -= 32768;
    if (i < 32768) { fW1p[i] = f2b(fW1[i]); return; }  // [256][128]
    i -= 32768;
    if (i < 32768) {                                   // fW2p [128(pad)][256]
        int n = i / 256;
        fW2p[i] = (n < 64) ? f2b(fW2[i]) : (short)0;
        return;
    }
    i -= 32768;
    if (i < 8192) { eW2p[i] = f2b(eW2[i]); return; }   // [128][64]
}

// ---------- embedding layer 1 ----------
__global__ __launch_bounds__(256) void embed1_k(const float* inp, const float* laneC,
                                                const float* eW1, const float* eb1, short* h1) {
    int g = threadIdx.x >> 6, j = threadIdx.x & 63;
    int t = blockIdx.x >> 10;
    int s = ((blockIdx.x & 1023) << 2) + g;
    float lc = laneC[s];
    size_t rin = ((size_t)s * 64 + t) * 3;
    float x0 = inp[rin] * lc, x1 = inp[rin + 1] * lc, x2 = inp[rin + 2] * lc;
    float h = fmaxf(eW1[j * 3] * x0 + eW1[j * 3 + 1] * x1 + eW1[j * 3 + 2] * x2 + eb1[j], 0.f);
    h1[((size_t)t * 4096 + s) * 64 + j] = f2b(h);
}

// ---------- generic bf16 MFMA GEMM (embed layer2 + head) ----------
__global__ __launch_bounds__(256) void gemm_k(const short* A1, int K1, const short* A2, int K2,
                                              const short* B, int Kt, const float* bias,
                                              float* outF, short* outB, int Nstore, int Nreal,
                                              int relu) {
    __shared__ alignas(16) short As[128 * 32];
    __shared__ alignas(16) short Bs[128 * 32];
    int tid = threadIdx.x;
    int wave = tid >> 6, lane = tid & 63;
    int m0 = blockIdx.x * 128, n0 = blockIdx.y * 128;

    f32x4 acc[4][4];
    #pragma unroll
    for (int i = 0; i < 4; ++i)
        #pragma unroll
        for (int j = 0; j < 4; ++j) acc[i][j] = (f32x4){0.f, 0.f, 0.f, 0.f};

    const int lr = lane & 15, lk8 = (lane >> 4) * 8;
    const int am = (wave & 1) * 64, bn = (wave >> 1) * 64;
    const int row = tid >> 2, c8 = (tid & 3) * 8;
    int nK = Kt / 32;

    for (int kt = 0; kt < nK; ++kt) {
        int kk = kt * 32;
        const short* Asrc; int astr, acol;
        if (kk < K1) { Asrc = A1; astr = K1; acol = kk; }
        else         { Asrc = A2; astr = K2; acol = kk - K1; }
        short8 a0 = *(const short8*)(Asrc + (size_t)(m0 + row) * astr + acol + c8);
        short8 a1 = *(const short8*)(Asrc + (size_t)(m0 + 64 + row) * astr + acol + c8);
        short8 b0 = *(const short8*)(B + (size_t)(n0 + row) * Kt + kk + c8);
        short8 b1 = *(const short8*)(B + (size_t)(n0 + 64 + row) * Kt + kk + c8);
        __syncthreads();
        *(short8*)&As[tid * 8] = a0;
        *(short8*)&As[(tid + 256) * 8] = a1;
        *(short8*)&Bs[tid * 8] = b0;
        *(short8*)&Bs[(tid + 256) * 8] = b1;
        __syncthreads();
        bf16x8 af[4], bfr[4];
        #pragma unroll
        for (int i = 0; i < 4; ++i) af[i]  = *(const bf16x8*)&As[(am + i * 16 + lr) * 32 + lk8];
        #pragma unroll
        for (int j = 0; j < 4; ++j) bfr[j] = *(const bf16x8*)&Bs[(bn + j * 16 + lr) * 32 + lk8];
        #pragma unroll
        for (int i = 0; i < 4; ++i)
            #pragma unroll
            for (int j = 0; j < 4; ++j)
                acc[i][j] = __builtin_amdgcn_mfma_f32_16x16x32_bf16(af[i], bfr[j], acc[i][j], 0, 0, 0);
    }

    int r0 = m0 + am + (lane >> 4) * 4;
    int c0 = n0 + bn + (lane & 15);
    #pragma unroll
    for (int j = 0; j < 4; ++j) {
        int col = c0 + j * 16;
        if (col >= Nreal) continue;
        float bs = bias[col];
        #pragma unroll
        for (int i = 0; i < 4; ++i) {
            #pragma unroll
            for (int r = 0; r < 4; ++r) {
                int rw = r0 + i * 16 + r;
                float v = acc[i][j][r] + bs;
                if (relu) v = fmaxf(v, 0.f);
                size_t o = (size_t)rw * Nstore + col;
                if (outF) outF[o] = v;
                if (outB) outB[o] = f2b(v);
            }
        }
    }
}

// ---------- persistent fused LSTM v5 ----------
// 128 blocks x 256 THREADS (4 waves) — hipcc pins 512-thread kernels to 128 VGPR (rounds 3-6
// all spilled); 256-thread kernels verifiably get 164+ VGPR. Block owns 32 s-rows.
// Wave w owns j in [64w,64w+64) x 4 gates = 16 col-frags; acc[2 rg][16 f] = 128 VGPR.
// ALL W streamed from L2 each step: 12 chunks, each wave loads its own 16KB slice
// (16 x global_load_lds) into a 2-slot LDS ring; wave-local counted vmcnt(16), vmcnt(0)
// only at the last chunk. xs via source-XOR-swizzled global_load_lds (conflict-free reads).
// Conv over hidden dim via __shfl across 4 j-slices + 1KB cross-wave edge buffers.
__global__ __launch_bounds__(256, 1) void lstm_k(const short* xs, const short* pW3,
                                                 const float* biasP,
                                                 const float* convw, const float* convb,
                                                 short* Hd, short* Cd, short* predictb) {
    __shared__ alignas(16) short Wbuf[2][4][8192];   // [slot][wave][f*512 + l*8]   (128 KB)
    __shared__ alignas(16) short xs_lds[4096];       // [s][ocp][8], ocp=oc^(s&7)   (8 KB)
    __shared__ alignas(16) short hfrag[8192];        // [oct][rg][srow][e]          (16 KB)
    __shared__ float edgeA[4][32];                   // hraw at j=64w   (per s)
    __shared__ float edgeB[4][32];                   // hraw at j=64w+63(per s)

    const int tid = threadIdx.x;
    const int w = tid >> 6, l = tid & 63;
    const int lj = l & 15, lk = l >> 4;
    const int sb = blockIdx.x * 32;

    float biasv[16];
    #pragma unroll
    for (int f = 0; f < 16; ++f) biasv[f] = biasP[w * 256 + f * 16 + lj];
    float creg[2][4][4] = {};
    const float cw0 = convw[0], cw1 = convw[1], cw2 = convw[2], cb = convb[0];

    for (int i = tid; i < 8192; i += 256) hfrag[i] = 0;

    auto issueW = [&](int kc, int pp) {
        const short* src = pW3 + (((size_t)kc * 4 + w) << 13) + l * 8;
        short* dst = &Wbuf[pp][w][l * 8];
        #pragma unroll
        for (int f = 0; f < 16; ++f)
            __builtin_amdgcn_global_load_lds(
                (const __attribute__((address_space(1))) void*)(src + f * 512),
                (__attribute__((address_space(3))) void*)(dst + f * 512), 16, 0, 0);
    };
    // xs tile [32 s][16 oc] in 16B chunks; LDS pos [s][ocp] holds global octet ocp^(s&7)
    auto issueXs = [&](int it) {
        #pragma unroll
        for (int q = 0; q < 2; ++q) {
            int idx = q * 256 + tid;
            int s = idx >> 4, ocp = idx & 15;
            const short* src = xs + ((size_t)it * 4096 + sb + s) * 128 + ((ocp ^ (s & 7)) << 3);
            __builtin_amdgcn_global_load_lds(
                (const __attribute__((address_space(1))) void*)src,
                (__attribute__((address_space(3))) void*)&xs_lds[idx * 8], 16, 0, 0);
        }
    };

    issueXs(0);            // 2 ops
    issueW(0, 0);          // 16 ops
    issueW(1, 1);          // 16 ops
    asm volatile("s_waitcnt vmcnt(16)" ::: "memory");   // xs + W0 landed; W1 in flight
    __syncthreads();                                    // (drains; prologue only)

    for (int k = 0; k < 65; ++k) {
        f32x4 acc[2][16];
        #pragma unroll
        for (int rg = 0; rg < 2; ++rg)
            #pragma unroll
            for (int f = 0; f < 16; ++f)
                acc[rg][f] = (f32x4){biasv[f], biasv[f], biasv[f], biasv[f]};

        #pragma unroll
        for (int kc = 0; kc < 12; ++kc) {
            if (kc == 11)      { asm volatile("s_waitcnt vmcnt(0)" ::: "memory"); }
            else if (kc >= 1)  { asm volatile("s_waitcnt vmcnt(16)" ::: "memory"); }
            const int p = kc & 1;
            bf16x8 af0, af1;
            if (kc < 4) {
                const int oc0 = ((kc * 4 + lk) ^ (lj & 7)) << 3;
                af0 = *(const bf16x8*)&xs_lds[lj * 128 + oc0];
                af1 = *(const bf16x8*)&xs_lds[(16 + lj) * 128 + oc0];
            } else {
                const int oct = (kc - 4) * 4 + lk;
                af0 = *(const bf16x8*)&hfrag[((oct * 2 + 0) * 16 + lj) * 8];
                af1 = *(const bf16x8*)&hfrag[((oct * 2 + 1) * 16 + lj) * 8];
            }
            #pragma unroll
            for (int f = 0; f < 16; ++f) {
                bf16x8 wf = *(const bf16x8*)&Wbuf[p][w][f * 512 + l * 8];
                acc[0][f] = __builtin_amdgcn_mfma_f32_16x16x32_bf16(af0, wf, acc[0][f], 0, 0, 0);
                acc[1][f] = __builtin_amdgcn_mfma_f32_16x16x32_bf16(af1, wf, acc[1][f], 0, 0, 0);
            }
            if (kc <= 9) issueW(kc + 2, p);   // refill just-consumed slot (DMA lands >> ds_read)
        }

        // ---- activations + cell update (registers) ----
        float hr[2][4][4];
        #pragma unroll
        for (int rg = 0; rg < 2; ++rg)
            #pragma unroll
            for (int js = 0; js < 4; ++js)
                #pragma unroll
                for (int r = 0; r < 4; ++r) {
                    float gi = acc[rg][js][r],     gf = acc[rg][4 + js][r];
                    float gg = acc[rg][8 + js][r], go = acc[rg][12 + js][r];
                    float c = sigf(gf) * creg[rg][js][r] + sigf(gi) * tanhf_fast(gg);
                    creg[rg][js][r] = c;
                    hr[rg][js][r] = sigf(go) * tanhf_fast(c);
                }
        if (lj == 0) {
            #pragma unroll
            for (int rg = 0; rg < 2; ++rg)
                #pragma unroll
                for (int r = 0; r < 4; ++r) edgeA[w][rg * 16 + 4 * lk + r] = hr[rg][0][r];
        }
        if (lj == 15) {
            #pragma unroll
            for (int rg = 0; rg < 2; ++rg)
                #pragma unroll
                for (int r = 0; r < 4; ++r) edgeB[w][rg * 16 + 4 * lk + r] = hr[rg][3][r];
        }
        asm volatile("s_waitcnt lgkmcnt(0)" ::: "memory");
        __builtin_amdgcn_s_barrier();          // MFMA LDS reads done; edges visible

        // ---- conv over hidden dim (shuffles), h feedback + outputs ----
        const int tslot = (k < 48) ? k : k - 1;
        const bool doW = (k != 48);
        const int pslot = k - 49;
        #pragma unroll
        for (int rg = 0; rg < 2; ++rg)
            #pragma unroll
            for (int r = 0; r < 4; ++r) {
                const int s = rg * 16 + 4 * lk + r;
                float v[4], nl[4], nr[4];
                #pragma unroll
                for (int js = 0; js < 4; ++js) v[js] = hr[rg][js][r];
                #pragma unroll
                for (int js = 0; js < 4; ++js) {
                    float sR = __shfl(v[js], l + 1, 64);
                    float sL = __shfl(v[js], l - 1, 64);
                    float cR = __shfl(v[js < 3 ? js + 1 : 3], l - 15, 64);
                    float cL = __shfl(v[js > 0 ? js - 1 : 0], l + 15, 64);
                    nr[js] = (lj < 15) ? sR : (js < 3 ? cR : (w < 3 ? edgeA[w + 1][s] : 0.f));
                    nl[js] = (lj > 0)  ? sL : (js > 0 ? cL : (w > 0 ? edgeB[w - 1][s] : 0.f));
                }
                const int ss = sb + s;
                const size_t o0 = ((size_t)ss * 64 + tslot) * 256;
                const size_t po = ((size_t)ss * 16 + (pslot >= 0 ? pslot : 0)) * 256;
                #pragma unroll
                for (int js = 0; js < 4; ++js) {
                    float h = cw0 * nl[js] + cw1 * v[js] + cw2 * nr[js] + cb;
                    const int j = 64 * w + 16 * js + lj;
                    const int oct = j >> 3;
                    hfrag[((oct * 2 + rg) * 16 + 4 * lk + r) * 8 + (lj & 7)] = f2b(h);
                    if (doW) {
                        Hd[o0 + j] = f2b(h);
                        Cd[o0 + j] = f2b(creg[rg][js][r]);
                    }
                    if (pslot >= 0) predictb[po + j] = f2b(h);
                }
            }

        // ---- next-step prefetch AFTER stores ----
        if (k < 64) {
            issueXs((k + 1 <= 48) ? k + 1 : k);   // 2 ops
            issueW(0, 0);                          // 16
            issueW(1, 1);                          // 16
        }
        asm volatile("s_waitcnt vmcnt(16)" ::: "memory");   // stores+xs+W0 retired; W1 flying
        asm volatile("s_waitcnt lgkmcnt(0)" ::: "memory");
        __builtin_amdgcn_s_barrier();                       // hfrag + xs ready for next step
    }
    asm volatile("s_waitcnt vmcnt(0)" ::: "memory");
}

// ---------- staged bf16 [s][t][j] -> output f32 [s][j][t] transpose ----------
__global__ __launch_bounds__(256) void transpose_k(const short* Hs, const short* Cs,
                                                   float* Ho, float* Co) {
    __shared__ short tile[64][132];
    int s = blockIdx.x, jh = blockIdx.y;
    const short* src = blockIdx.z ? Cs : Hs;
    float* dst = blockIdx.z ? Co : Ho;
    #pragma unroll 4
    for (int i = 0; i < 16; ++i) {
        int idx = i * 256 + threadIdx.x;              // over 4096 short2
        int t = idx >> 6, jj2 = idx & 63;
        *(int*)&tile[t][jj2 * 2] =
            *(const int*)&src[((size_t)s * 64 + t) * 256 + jh * 128 + jj2 * 2];
    }
    __syncthreads();
    #pragma unroll 4
    for (int i = 0; i < 32; ++i) {
        int idx = i * 256 + threadIdx.x;              // over 8192
        int jj = idx >> 6, t = idx & 63;
        dst[((size_t)s * 256 + jh * 128 + jj) * 64 + t] = b2f(tile[t][jj]);
    }
}

// ---------- final: fc3 (64->1) + divide by laneC ----------
__global__ __launch_bounds__(256) void final_k(const short* t2b, const float* fW3, const float* fb3,
                                               const float* laneC, float* out0) {
    int r = blockIdx.x * 256 + threadIdx.x;
    float acc = fb3[0];
    const short* rowp = t2b + (size_t)r * 64;
    #pragma unroll 8
    for (int k = 0; k < 64; ++k) acc += b2f(rowp[k]) * fW3[k];
    out0[r] = acc / laneC[r >> 4];
}

// ---------- host ----------
extern "C" void kernel_launch(void* const* d_in, const int* in_sizes, int n_in,
                              void* d_out, int out_size, void* d_ws, size_t ws_size,
                              hipStream_t stream) {
    (void)in_sizes; (void)n_in; (void)out_size; (void)ws_size;
    const float* inputData = (const float*)d_in[0];
    const float* lane  = (const float*)d_in[1];
    const float* lgW1  = (const float*)d_in[2];  const float* lgb1 = (const float*)d_in[3];
    const float* lgW2  = (const float*)d_in[4];  const float* lgb2 = (const float*)d_in[5];
    const float* eW1   = (const float*)d_in[6];  const float* eb1  = (const float*)d_in[7];
    const float* eW2   = (const float*)d_in[8];  const float* eb2  = (const float*)d_in[9];
    const float* Wih   = (const float*)d_in[10]; const float* Whh  = (const float*)d_in[11];
    const float* bih   = (const float*)d_in[12]; const float* bhh  = (const float*)d_in[13];
    const float* convw = (const float*)d_in[14]; const float* convb= (const float*)d_in[15];
    const float* oW    = (const float*)d_in[16]; const float* ob   = (const float*)d_in[17];
    const float* fW1   = (const float*)d_in[18]; const float* fb1  = (const float*)d_in[19];
    const float* fW2   = (const float*)d_in[20]; const float* fb2  = (const float*)d_in[21];
    const float* fW3   = (const float*)d_in[22]; const float* fb3  = (const float*)d_in[23];

    float* out0 = (float*)d_out;
    float* Hout = out0 + 65536;
    float* Cout = Hout + (size_t)67108864;

    char* w = (char*)d_ws;
    size_t off = 0;
    auto alloc = [&](size_t bytes) -> void* {
        void* p = w + off;
        off += (bytes + 255) & ~(size_t)255;
        return p;
    };
    float* laneC    = (float*)alloc(4096 * 4);
    float* biasP    = (float*)alloc(1024 * 4);
    short* pW3      = (short*)alloc((size_t)1024 * 384 * 2);
    short* oWp      = (short*)alloc((size_t)128 * 256 * 2);
    short* fW1p     = (short*)alloc((size_t)256 * 128 * 2);
    short* fW2p     = (short*)alloc((size_t)128 * 256 * 2);
    short* eW2p     = (short*)alloc((size_t)128 * 64 * 2);
    short* h1       = (short*)alloc((size_t)64 * 4096 * 64 * 2);
    short* xs       = (short*)alloc((size_t)64 * 4096 * 128 * 2);
    short* predictb = (short*)alloc((size_t)65536 * 256 * 2);
    short* t0b      = (short*)alloc((size_t)65536 * 128 * 2);
    short* t1b      = (short*)alloc((size_t)65536 * 256 * 2);
    short* t2b      = (short*)alloc((size_t)65536 * 64 * 2);
    short* Hstage   = (short*)alloc((size_t)4096 * 64 * 256 * 2);
    short* Cstage   = (short*)alloc((size_t)4096 * 64 * 256 * 2);

    lanec_k<<<16, 256, 0, stream>>>(lane, lgW1, lgb1, lgW2, lgb2, laneC);
    {
        int total = 393216 + 1024 + 32768 + 32768 + 32768 + 8192;
        pack_k<<<(total + 255) / 256, 256, 0, stream>>>(Wih, Whh, bih, bhh, oW, fW1, fW2, eW2,
                                                        pW3, biasP, oWp, fW1p, fW2p, eW2p);
    }
    embed1_k<<<65536, 256, 0, stream>>>(inputData, laneC, eW1, eb1, h1);
    gemm_k<<<dim3(2048, 1), 256, 0, stream>>>(h1, 64, (const short*)nullptr, 0, eW2p, 64,
                                              eb2, (float*)nullptr, xs, 128, 128, 1);

    lstm_k<<<128, 256, 0, stream>>>(xs, pW3, biasP, convw, convb, Hstage, Cstage, predictb);

    transpose_k<<<dim3(4096, 2, 2), 256, 0, stream>>>(Hstage, Cstage, Hout, Cout);

    gemm_k<<<dim3(512, 1), 256, 0, stream>>>(predictb, 256, (const short*)nullptr, 0, oWp, 256,
                                             ob, (float*)nullptr, t0b, 128, 128, 0);
    gemm_k<<<dim3(512, 2), 256, 0, stream>>>(t0b, 128, (const short*)nullptr, 0, fW1p, 128,
                                             fb1, (float*)nullptr, t1b, 256, 256, 1);
    gemm_k<<<dim3(512, 1), 256, 0, stream>>>(t1b, 256, (const short*)nullptr, 0, fW2p, 256,
                                             fb2, (float*)nullptr, t2b, 64, 64, 1);
    final_k<<<256, 256, 0, stream>>>(t2b, fW3, fb3, laneC, out0);
}

// Round 10
// 1809.534 us; speedup vs baseline: 2.4054x; 2.4054x over previous
//
#include <hip/hip_runtime.h>
#include <hip/hip_bf16.h>
#include <stdint.h>

// ---------- types ----------
using f32x4  = __attribute__((ext_vector_type(4))) float;
using bf16x8 = __attribute__((ext_vector_type(8))) __bf16;
using short8 = __attribute__((ext_vector_type(8))) short;

__device__ __forceinline__ short f2b(float f) {
    unsigned u = __builtin_bit_cast(unsigned, f);
    unsigned r = (u + 0x7fff + ((u >> 16) & 1)) >> 16;   // RNE
    return (short)r;
}
__device__ __forceinline__ float b2f(short s) {
    unsigned u = ((unsigned)(unsigned short)s) << 16;
    return __builtin_bit_cast(float, u);
}
__device__ __forceinline__ float sigf(float x) {
    return __builtin_amdgcn_rcpf(1.f + __expf(-x));
}
__device__ __forceinline__ float tanhf_fast(float x) {
    x = fminf(fmaxf(x, -15.f), 15.f);
    return 2.f * __builtin_amdgcn_rcpf(1.f + __expf(-2.f * x)) - 1.f;
}

// ---------- laneGate ----------
__global__ __launch_bounds__(256) void lanec_k(const float* lane, const float* W1, const float* b1,
                                               const float* W2, const float* b2, float* laneC) {
    int s = blockIdx.x * 256 + threadIdx.x;
    float v = lane[s];
    float acc = b2[0];
    #pragma unroll
    for (int k = 0; k < 32; ++k) {
        float t = fmaxf(v * W1[k] + b1[k], 0.f);
        acc += t * W2[k];
    }
    laneC[s] = 1.f / (1.f + __expf(-acc));
}

// ---------- weight packing ----------
// pW2: MFMA-frag-major [12 kc][64 fg][64 lane][8 e], fg = w*8 + f, f = g*2 + u.
// (w,u,lj) -> j = 32w + 16u + lj; gate g; combined row n = g*256 + j.
// k = kc*32 + lk*8 + e (k<128 -> Wih col, else Whh col k-128).
__global__ __launch_bounds__(256) void pack_k(const float* Wih, const float* Whh, const float* bih,
                                              const float* bhh, const float* oW, const float* fW1,
                                              const float* fW2, const float* eW2,
                                              short* pW2, float* biasP,
                                              short* oWp, short* fW1p, short* fW2p, short* eW2p) {
    int i = blockIdx.x * 256 + threadIdx.x;
    if (i < 393216) {
        int e = i & 7, l = (i >> 3) & 63, fg = (i >> 9) & 63, kc = i >> 15;
        int w = fg >> 3, f = fg & 7;
        int lj = l & 15, lk = l >> 4;
        int g = f >> 1, u = f & 1;
        int j = 32 * w + 16 * u + lj;
        int n = g * 256 + j;
        int k = kc * 32 + lk * 8 + e;
        pW2[i] = f2b(k < 128 ? Wih[n * 128 + k] : Whh[n * 256 + (k - 128)]);
        return;
    }
    i -= 393216;
    if (i < 1024) {                                    // biasP[w*128 + f*16 + lj]
        int lj = i & 15, f = (i >> 4) & 7, w = i >> 7;
        int g = f >> 1, u = f & 1;
        int j = 32 * w + 16 * u + lj;
        int n = g * 256 + j;
        biasP[i] = bih[n] + bhh[n];
        return;
    }
    i -= 1024;
    if (i < 32768) { oWp[i] = f2b(oW[i]); return; }    // [128][256]
    i -= 32768;
    if (i < 32768) { fW1p[i] = f2b(fW1[i]); return; }  // [256][128]
    i -= 32768;
    if (i < 32768) {                                   // fW2p [128(pad)][256]
        int n = i / 256;
        fW2p[i] = (n < 64) ? f2b(fW2[i]) : (short)0;
        return;
    }
    i -= 32768;
    if (i < 8192) { eW2p[i] = f2b(eW2[i]); return; }   // [128][64]
}

// ---------- embedding layer 1 ----------
__global__ __launch_bounds__(256) void embed1_k(const float* inp, const float* laneC,
                                                const float* eW1, const float* eb1, short* h1) {
    int g = threadIdx.x >> 6, j = threadIdx.x & 63;
    int t = blockIdx.x >> 10;
    int s = ((blockIdx.x & 1023) << 2) + g;
    float lc = laneC[s];
    size_t rin = ((size_t)s * 64 + t) * 3;
    float x0 = inp[rin] * lc, x1 = inp[rin + 1] * lc, x2 = inp[rin + 2] * lc;
    float h = fmaxf(eW1[j * 3] * x0 + eW1[j * 3 + 1] * x1 + eW1[j * 3 + 2] * x2 + eb1[j], 0.f);
    h1[((size_t)t * 4096 + s) * 64 + j] = f2b(h);
}

// ---------- generic bf16 MFMA GEMM (embed layer2 + head) ----------
__global__ __launch_bounds__(256) void gemm_k(const short* A1, int K1, const short* A2, int K2,
                                              const short* B, int Kt, const float* bias,
                                              float* outF, short* outB, int Nstore, int Nreal,
                                              int relu) {
    __shared__ alignas(16) short As[128 * 32];
    __shared__ alignas(16) short Bs[128 * 32];
    int tid = threadIdx.x;
    int wave = tid >> 6, lane = tid & 63;
    int m0 = blockIdx.x * 128, n0 = blockIdx.y * 128;

    f32x4 acc[4][4];
    #pragma unroll
    for (int i = 0; i < 4; ++i)
        #pragma unroll
        for (int j = 0; j < 4; ++j) acc[i][j] = (f32x4){0.f, 0.f, 0.f, 0.f};

    const int lr = lane & 15, lk8 = (lane >> 4) * 8;
    const int am = (wave & 1) * 64, bn = (wave >> 1) * 64;
    const int row = tid >> 2, c8 = (tid & 3) * 8;
    int nK = Kt / 32;

    for (int kt = 0; kt < nK; ++kt) {
        int kk = kt * 32;
        const short* Asrc; int astr, acol;
        if (kk < K1) { Asrc = A1; astr = K1; acol = kk; }
        else         { Asrc = A2; astr = K2; acol = kk - K1; }
        short8 a0 = *(const short8*)(Asrc + (size_t)(m0 + row) * astr + acol + c8);
        short8 a1 = *(const short8*)(Asrc + (size_t)(m0 + 64 + row) * astr + acol + c8);
        short8 b0 = *(const short8*)(B + (size_t)(n0 + row) * Kt + kk + c8);
        short8 b1 = *(const short8*)(B + (size_t)(n0 + 64 + row) * Kt + kk + c8);
        __syncthreads();
        *(short8*)&As[tid * 8] = a0;
        *(short8*)&As[(tid + 256) * 8] = a1;
        *(short8*)&Bs[tid * 8] = b0;
        *(short8*)&Bs[(tid + 256) * 8] = b1;
        __syncthreads();
        bf16x8 af[4], bfr[4];
        #pragma unroll
        for (int i = 0; i < 4; ++i) af[i]  = *(const bf16x8*)&As[(am + i * 16 + lr) * 32 + lk8];
        #pragma unroll
        for (int j = 0; j < 4; ++j) bfr[j] = *(const bf16x8*)&Bs[(bn + j * 16 + lr) * 32 + lk8];
        #pragma unroll
        for (int i = 0; i < 4; ++i)
            #pragma unroll
            for (int j = 0; j < 4; ++j)
                acc[i][j] = __builtin_amdgcn_mfma_f32_16x16x32_bf16(af[i], bfr[j], acc[i][j], 0, 0, 0);
    }

    int r0 = m0 + am + (lane >> 4) * 4;
    int c0 = n0 + bn + (lane & 15);
    #pragma unroll
    for (int j = 0; j < 4; ++j) {
        int col = c0 + j * 16;
        if (col >= Nreal) continue;
        float bs = bias[col];
        #pragma unroll
        for (int i = 0; i < 4; ++i) {
            #pragma unroll
            for (int r = 0; r < 4; ++r) {
                int rw = r0 + i * 16 + r;
                float v = acc[i][j][r] + bs;
                if (relu) v = fmaxf(v, 0.f);
                size_t o = (size_t)rw * Nstore + col;
                if (outF) outF[o] = v;
                if (outB) outB[o] = f2b(v);
            }
        }
    }
}

// ---------- persistent fused LSTM v6.1 ----------
// 256 blocks x 512 threads (8 waves) x 16 s-rows — full GPU, ~105 live VGPR (no spill).
// ALL W streamed from L2 per step: 12 chunks x 8KB/wave, 2-slot LDS ring.
// RACE FIX vs v6 (round 8 post-timing divergence): per-step conv issues FIFO
// [W0(8), W1(8), ax(4), stores(S)] where S varies 0/16/24 by step. In-order VMEM
// retirement => "W_kc retired" iff outstanding <= #ops issued after W_kc:
//   kc=0: 12+S >= 12 -> vmcnt(12);  kc=1: 4+S+8 >= 12 -> vmcnt(12)  (S-independent)
//   kc in [2,10]: exactly 8 (only W_{kc+1}) -> vmcnt(8);  kc=11: 0 -> vmcnt(0).
// Round 8's vmcnt(24)@kc0 + no-wait@kc1 raced when S=0 (step 48).
__global__ __launch_bounds__(512) void lstm_k(const short* xs, const short* pW2, const float* biasP,
                                              const float* convw, const float* convb,
                                              short* Hd, short* Cd, short* predictb) {
    __shared__ alignas(16) short Wbuf[2][8][4096];   // [slot][wave][f*512 + l*8]  (128 KB)
    __shared__ alignas(16) short hfrag[4096];        // [oct 32][s 16][e 8]        (8 KB)
    __shared__ float edgeA[8][16];                   // hraw at j=32w    (per s)
    __shared__ float edgeB[8][16];                   // hraw at j=32w+31 (per s)

    const int tid = threadIdx.x;
    const int w = tid >> 6, l = tid & 63;
    const int lj = l & 15, lk = l >> 4;
    const int sb = blockIdx.x * 16;

    float biasv[8];
    #pragma unroll
    for (int f = 0; f < 8; ++f) biasv[f] = biasP[w * 128 + f * 16 + lj];
    float creg[2][4] = {};
    const float cw0 = convw[0], cw1 = convw[1], cw2 = convw[2], cb = convb[0];

    for (int i = tid; i < 4096; i += 512) hfrag[i] = 0;

    auto issueW = [&](int kc, int pp) {
        const short* src = pW2 + (((size_t)kc * 64 + w * 8) << 9) + l * 8;
        short* dst = &Wbuf[pp][w][l * 8];
        #pragma unroll
        for (int ri = 0; ri < 8; ++ri)
            __builtin_amdgcn_global_load_lds(
                (const __attribute__((address_space(1))) void*)(src + ri * 512),
                (__attribute__((address_space(3))) void*)(dst + ri * 512), 16, 0, 0);
    };

    bf16x8 ax[4];
    auto loadAx = [&](int it) {
        #pragma unroll
        for (int kc = 0; kc < 4; ++kc)
            ax[kc] = *(const bf16x8*)(xs + ((size_t)it * 4096 + sb + lj) * 128 + kc * 32 + lk * 8);
    };

    issueW(0, 0);
    issueW(1, 1);
    loadAx(0);
    __syncthreads();                // hfrag zeros visible (prologue drain is fine)

    for (int k = 0; k < 65; ++k) {
        f32x4 acc[8];
        #pragma unroll
        for (int f = 0; f < 8; ++f) acc[f] = (f32x4){biasv[f], biasv[f], biasv[f], biasv[f]};

        #pragma unroll
        for (int kc = 0; kc < 12; ++kc) {
            if (kc <= 1)       { asm volatile("s_waitcnt vmcnt(12)" ::: "memory"); }
            else if (kc == 11) { asm volatile("s_waitcnt vmcnt(0)" ::: "memory"); }
            else               { asm volatile("s_waitcnt vmcnt(8)" ::: "memory"); }
            const int p = kc & 1;
            bf16x8 af;
            if (kc < 4) af = ax[kc];
            else        af = *(const bf16x8*)&hfrag[(((kc - 4) * 4 + lk) * 16 + lj) * 8];
            #pragma unroll
            for (int f = 0; f < 8; ++f) {
                bf16x8 wf = *(const bf16x8*)&Wbuf[p][w][f * 512 + l * 8];
                acc[f] = __builtin_amdgcn_mfma_f32_16x16x32_bf16(af, wf, acc[f], 0, 0, 0);
            }
            if (kc <= 9) issueW(kc + 2, p);   // refill just-consumed slot
        }

        // ---- activations + cell update (registers) ----
        float hr[2][4];
        #pragma unroll
        for (int u = 0; u < 2; ++u)
            #pragma unroll
            for (int r = 0; r < 4; ++r) {
                float gi = acc[u][r],     gf = acc[2 + u][r];
                float gg = acc[4 + u][r], go = acc[6 + u][r];
                float c = sigf(gf) * creg[u][r] + sigf(gi) * tanhf_fast(gg);
                creg[u][r] = c;
                hr[u][r] = sigf(go) * tanhf_fast(c);
            }
        if (lj == 0) {
            #pragma unroll
            for (int r = 0; r < 4; ++r) edgeA[w][4 * lk + r] = hr[0][r];
        }
        if (lj == 15) {
            #pragma unroll
            for (int r = 0; r < 4; ++r) edgeB[w][4 * lk + r] = hr[1][r];
        }
        asm volatile("s_waitcnt lgkmcnt(0)" ::: "memory");
        __builtin_amdgcn_s_barrier();         // kc-loop hfrag reads done; edges visible

        // ---- prefetch next step FIRST (before stores -> S-independent vmcnt FIFO) ----
        if (k < 64) {
            issueW(0, 0);                      // 8 ops
            issueW(1, 1);                      // 8 ops
            loadAx((k + 1 <= 48) ? k + 1 : k); // 4 reg loads
        }

        // ---- conv over hidden dim (shuffles), h feedback + outputs ----
        const int tslot = (k < 48) ? k : k - 1;
        const bool doW = (k != 48);
        const int pslot = k - 49;
        #pragma unroll
        for (int r = 0; r < 4; ++r) {
            const int s = 4 * lk + r;
            float v0 = hr[0][r], v1 = hr[1][r];
            float s0r = __shfl(v0, l + 1, 64);
            float s0l = __shfl(v0, l - 1, 64);
            float s1r = __shfl(v1, l + 1, 64);
            float s1l = __shfl(v1, l - 1, 64);
            float x01 = __shfl(v1, l - 15, 64);   // lj==15,u0: right = (u1,lj0)
            float x10 = __shfl(v0, l + 15, 64);   // lj==0, u1: left  = (u0,lj15)
            float n0r = (lj < 15) ? s0r : x01;
            float n0l = (lj > 0) ? s0l : (w > 0 ? edgeB[w - 1][s] : 0.f);
            float n1r = (lj < 15) ? s1r : (w < 7 ? edgeA[w + 1][s] : 0.f);
            float n1l = (lj > 0) ? s1l : x10;
            float h0 = cw0 * n0l + cw1 * v0 + cw2 * n0r + cb;
            float h1 = cw0 * n1l + cw1 * v1 + cw2 * n1r + cb;
            const int j0 = 32 * w + lj, j1 = j0 + 16;
            hfrag[(((j0 >> 3) * 16) + s) * 8 + (lj & 7)] = f2b(h0);
            hfrag[(((j1 >> 3) * 16) + s) * 8 + (lj & 7)] = f2b(h1);
            const int ss = sb + s;
            if (doW) {
                size_t o0 = ((size_t)ss * 64 + tslot) * 256;
                Hd[o0 + j0] = f2b(h0);
                Hd[o0 + j1] = f2b(h1);
                Cd[o0 + j0] = f2b(creg[0][r]);
                Cd[o0 + j1] = f2b(creg[1][r]);
            }
            if (pslot >= 0) {
                size_t po = ((size_t)ss * 16 + pslot) * 256;
                predictb[po + j0] = f2b(h0);
                predictb[po + j1] = f2b(h1);
            }
        }
        asm volatile("s_waitcnt lgkmcnt(0)" ::: "memory");
        __builtin_amdgcn_s_barrier();         // hfrag ready for next step (vmcnt NOT drained)
    }
    asm volatile("s_waitcnt vmcnt(0)" ::: "memory");
}

// ---------- staged bf16 [s][t][j] -> output f32 [s][j][t] transpose ----------
__global__ __launch_bounds__(256) void transpose_k(const short* Hs, const short* Cs,
                                                   float* Ho, float* Co) {
    __shared__ short tile[64][132];
    int s = blockIdx.x, jh = blockIdx.y;
    const short* src = blockIdx.z ? Cs : Hs;
    float* dst = blockIdx.z ? Co : Ho;
    #pragma unroll 4
    for (int i = 0; i < 16; ++i) {
        int idx = i * 256 + threadIdx.x;              // over 4096 short2
        int t = idx >> 6, jj2 = idx & 63;
        *(int*)&tile[t][jj2 * 2] =
            *(const int*)&src[((size_t)s * 64 + t) * 256 + jh * 128 + jj2 * 2];
    }
    __syncthreads();
    #pragma unroll 4
    for (int i = 0; i < 32; ++i) {
        int idx = i * 256 + threadIdx.x;              // over 8192
        int jj = idx >> 6, t = idx & 63;
        dst[((size_t)s * 256 + jh * 128 + jj) * 64 + t] = b2f(tile[t][jj]);
    }
}

// ---------- final: fc3 (64->1) + divide by laneC ----------
__global__ __launch_bounds__(256) void final_k(const short* t2b, const float* fW3, const float* fb3,
                                               const float* laneC, float* out0) {
    int r = blockIdx.x * 256 + threadIdx.x;
    float acc = fb3[0];
    const short* rowp = t2b + (size_t)r * 64;
    #pragma unroll 8
    for (int k = 0; k < 64; ++k) acc += b2f(rowp[k]) * fW3[k];
    out0[r] = acc / laneC[r >> 4];
}

// ---------- host ----------
extern "C" void kernel_launch(void* const* d_in, const int* in_sizes, int n_in,
                              void* d_out, int out_size, void* d_ws, size_t ws_size,
                              hipStream_t stream) {
    (void)in_sizes; (void)n_in; (void)out_size; (void)ws_size;
    const float* inputData = (const float*)d_in[0];
    const float* lane  = (const float*)d_in[1];
    const float* lgW1  = (const float*)d_in[2];  const float* lgb1 = (const float*)d_in[3];
    const float* lgW2  = (const float*)d_in[4];  const float* lgb2 = (const float*)d_in[5];
    const float* eW1   = (const float*)d_in[6];  const float* eb1  = (const float*)d_in[7];
    const float* eW2   = (const float*)d_in[8];  const float* eb2  = (const float*)d_in[9];
    const float* Wih   = (const float*)d_in[10]; const float* Whh  = (const float*)d_in[11];
    const float* bih   = (const float*)d_in[12]; const float* bhh  = (const float*)d_in[13];
    const float* convw = (const float*)d_in[14]; const float* convb= (const float*)d_in[15];
    const float* oW    = (const float*)d_in[16]; const float* ob   = (const float*)d_in[17];
    const float* fW1   = (const float*)d_in[18]; const float* fb1  = (const float*)d_in[19];
    const float* fW2   = (const float*)d_in[20]; const float* fb2  = (const float*)d_in[21];
    const float* fW3   = (const float*)d_in[22]; const float* fb3  = (const float*)d_in[23];

    float* out0 = (float*)d_out;
    float* Hout = out0 + 65536;
    float* Cout = Hout + (size_t)67108864;

    char* w = (char*)d_ws;
    size_t off = 0;
    auto alloc = [&](size_t bytes) -> void* {
        void* p = w + off;
        off += (bytes + 255) & ~(size_t)255;
        return p;
    };
    float* laneC    = (float*)alloc(4096 * 4);
    float* biasP    = (float*)alloc(1024 * 4);
    short* pW2      = (short*)alloc((size_t)1024 * 384 * 2);
    short* oWp      = (short*)alloc((size_t)128 * 256 * 2);
    short* fW1p     = (short*)alloc((size_t)256 * 128 * 2);
    short* fW2p     = (short*)alloc((size_t)128 * 256 * 2);
    short* eW2p     = (short*)alloc((size_t)128 * 64 * 2);
    short* h1       = (short*)alloc((size_t)64 * 4096 * 64 * 2);
    short* xs       = (short*)alloc((size_t)64 * 4096 * 128 * 2);
    short* predictb = (short*)alloc((size_t)65536 * 256 * 2);
    short* t0b      = (short*)alloc((size_t)65536 * 128 * 2);
    short* t1b      = (short*)alloc((size_t)65536 * 256 * 2);
    short* t2b      = (short*)alloc((size_t)65536 * 64 * 2);
    short* Hstage   = (short*)alloc((size_t)4096 * 64 * 256 * 2);
    short* Cstage   = (short*)alloc((size_t)4096 * 64 * 256 * 2);

    lanec_k<<<16, 256, 0, stream>>>(lane, lgW1, lgb1, lgW2, lgb2, laneC);
    {
        int total = 393216 + 1024 + 32768 + 32768 + 32768 + 8192;
        pack_k<<<(total + 255) / 256, 256, 0, stream>>>(Wih, Whh, bih, bhh, oW, fW1, fW2, eW2,
                                                        pW2, biasP, oWp, fW1p, fW2p, eW2p);
    }
    embed1_k<<<65536, 256, 0, stream>>>(inputData, laneC, eW1, eb1, h1);
    gemm_k<<<dim3(2048, 1), 256, 0, stream>>>(h1, 64, (const short*)nullptr, 0, eW2p, 64,
                                              eb2, (float*)nullptr, xs, 128, 128, 1);

    lstm_k<<<256, 512, 0, stream>>>(xs, pW2, biasP, convw, convb, Hstage, Cstage, predictb);

    transpose_k<<<dim3(4096, 2, 2), 256, 0, stream>>>(Hstage, Cstage, Hout, Cout);

    gemm_k<<<dim3(512, 1), 256, 0, stream>>>(predictb, 256, (const short*)nullptr, 0, oWp, 256,
                                             ob, (float*)nullptr, t0b, 128, 128, 0);
    gemm_k<<<dim3(512, 2), 256, 0, stream>>>(t0b, 128, (const short*)nullptr, 0, fW1p, 128,
                                             fb1, (float*)nullptr, t1b, 256, 256, 1);
    gemm_k<<<dim3(512, 1), 256, 0, stream>>>(t1b, 256, (const short*)nullptr, 0, fW2p, 256,
                                             fb2, (float*)nullptr, t2b, 64, 64, 1);
    final_k<<<256, 256, 0, stream>>>(t2b, fW3, fb3, laneC, out0);
}

// Round 11
// 1801.843 us; speedup vs baseline: 2.4157x; 1.0043x over previous
//
#include <hip/hip_runtime.h>
#include <hip/hip_bf16.h>
#include <stdint.h>

// ---------- types ----------
using f32x4  = __attribute__((ext_vector_type(4))) float;
using bf16x8 = __attribute__((ext_vector_type(8))) __bf16;
using short8 = __attribute__((ext_vector_type(8))) short;

__device__ __forceinline__ short f2b(float f) {
    unsigned u = __builtin_bit_cast(unsigned, f);
    unsigned r = (u + 0x7fff + ((u >> 16) & 1)) >> 16;   // RNE
    return (short)r;
}
__device__ __forceinline__ float b2f(short s) {
    unsigned u = ((unsigned)(unsigned short)s) << 16;
    return __builtin_bit_cast(float, u);
}
__device__ __forceinline__ float sigf(float x) {
    return __builtin_amdgcn_rcpf(1.f + __expf(-x));
}
__device__ __forceinline__ float tanhf_fast(float x) {
    x = fminf(fmaxf(x, -15.f), 15.f);
    return 2.f * __builtin_amdgcn_rcpf(1.f + __expf(-2.f * x)) - 1.f;
}

// ---------- laneGate ----------
__global__ __launch_bounds__(256) void lanec_k(const float* lane, const float* W1, const float* b1,
                                               const float* W2, const float* b2, float* laneC) {
    int s = blockIdx.x * 256 + threadIdx.x;
    float v = lane[s];
    float acc = b2[0];
    #pragma unroll
    for (int k = 0; k < 32; ++k) {
        float t = fmaxf(v * W1[k] + b1[k], 0.f);
        acc += t * W2[k];
    }
    laneC[s] = 1.f / (1.f + __expf(-acc));
}

// ---------- weight packing ----------
// pW2: MFMA-frag-major [12 kc][64 fg][64 lane][8 e], fg = w*8 + f, f = g*2 + u.
// (w,u,lj) -> j = 32w + 16u + lj; gate g; combined row n = g*256 + j.
// k = kc*32 + lk*8 + e (k<128 -> Wih col, else Whh col k-128).
__global__ __launch_bounds__(256) void pack_k(const float* Wih, const float* Whh, const float* bih,
                                              const float* bhh, const float* oW, const float* fW1,
                                              const float* fW2, const float* eW2,
                                              short* pW2, float* biasP,
                                              short* oWp, short* fW1p, short* fW2p, short* eW2p) {
    int i = blockIdx.x * 256 + threadIdx.x;
    if (i < 393216) {
        int e = i & 7, l = (i >> 3) & 63, fg = (i >> 9) & 63, kc = i >> 15;
        int w = fg >> 3, f = fg & 7;
        int lj = l & 15, lk = l >> 4;
        int g = f >> 1, u = f & 1;
        int j = 32 * w + 16 * u + lj;
        int n = g * 256 + j;
        int k = kc * 32 + lk * 8 + e;
        pW2[i] = f2b(k < 128 ? Wih[n * 128 + k] : Whh[n * 256 + (k - 128)]);
        return;
    }
    i -= 393216;
    if (i < 1024) {                                    // biasP[w*128 + f*16 + lj]
        int lj = i & 15, f = (i >> 4) & 7, w = i >> 7;
        int g = f >> 1, u = f & 1;
        int j = 32 * w + 16 * u + lj;
        int n = g * 256 + j;
        biasP[i] = bih[n] + bhh[n];
        return;
    }
    i -= 1024;
    if (i < 32768) { oWp[i] = f2b(oW[i]); return; }    // [128][256]
    i -= 32768;
    if (i < 32768) { fW1p[i] = f2b(fW1[i]); return; }  // [256][128]
    i -= 32768;
    if (i < 32768) {                                   // fW2p [128(pad)][256]
        int n = i / 256;
        fW2p[i] = (n < 64) ? f2b(fW2[i]) : (short)0;
        return;
    }
    i -= 32768;
    if (i < 8192) { eW2p[i] = f2b(eW2[i]); return; }   // [128][64]
}

// ---------- embedding layer 1 ----------
__global__ __launch_bounds__(256) void embed1_k(const float* inp, const float* laneC,
                                                const float* eW1, const float* eb1, short* h1) {
    int g = threadIdx.x >> 6, j = threadIdx.x & 63;
    int t = blockIdx.x >> 10;
    int s = ((blockIdx.x & 1023) << 2) + g;
    float lc = laneC[s];
    size_t rin = ((size_t)s * 64 + t) * 3;
    float x0 = inp[rin] * lc, x1 = inp[rin + 1] * lc, x2 = inp[rin + 2] * lc;
    float h = fmaxf(eW1[j * 3] * x0 + eW1[j * 3 + 1] * x1 + eW1[j * 3 + 2] * x2 + eb1[j], 0.f);
    h1[((size_t)t * 4096 + s) * 64 + j] = f2b(h);
}

// ---------- generic bf16 MFMA GEMM (embed layer2 + head) ----------
__global__ __launch_bounds__(256) void gemm_k(const short* A1, int K1, const short* A2, int K2,
                                              const short* B, int Kt, const float* bias,
                                              float* outF, short* outB, int Nstore, int Nreal,
                                              int relu) {
    __shared__ alignas(16) short As[128 * 32];
    __shared__ alignas(16) short Bs[128 * 32];
    int tid = threadIdx.x;
    int wave = tid >> 6, lane = tid & 63;
    int m0 = blockIdx.x * 128, n0 = blockIdx.y * 128;

    f32x4 acc[4][4];
    #pragma unroll
    for (int i = 0; i < 4; ++i)
        #pragma unroll
        for (int j = 0; j < 4; ++j) acc[i][j] = (f32x4){0.f, 0.f, 0.f, 0.f};

    const int lr = lane & 15, lk8 = (lane >> 4) * 8;
    const int am = (wave & 1) * 64, bn = (wave >> 1) * 64;
    const int row = tid >> 2, c8 = (tid & 3) * 8;
    int nK = Kt / 32;

    for (int kt = 0; kt < nK; ++kt) {
        int kk = kt * 32;
        const short* Asrc; int astr, acol;
        if (kk < K1) { Asrc = A1; astr = K1; acol = kk; }
        else         { Asrc = A2; astr = K2; acol = kk - K1; }
        short8 a0 = *(const short8*)(Asrc + (size_t)(m0 + row) * astr + acol + c8);
        short8 a1 = *(const short8*)(Asrc + (size_t)(m0 + 64 + row) * astr + acol + c8);
        short8 b0 = *(const short8*)(B + (size_t)(n0 + row) * Kt + kk + c8);
        short8 b1 = *(const short8*)(B + (size_t)(n0 + 64 + row) * Kt + kk + c8);
        __syncthreads();
        *(short8*)&As[tid * 8] = a0;
        *(short8*)&As[(tid + 256) * 8] = a1;
        *(short8*)&Bs[tid * 8] = b0;
        *(short8*)&Bs[(tid + 256) * 8] = b1;
        __syncthreads();
        bf16x8 af[4], bfr[4];
        #pragma unroll
        for (int i = 0; i < 4; ++i) af[i]  = *(const bf16x8*)&As[(am + i * 16 + lr) * 32 + lk8];
        #pragma unroll
        for (int j = 0; j < 4; ++j) bfr[j] = *(const bf16x8*)&Bs[(bn + j * 16 + lr) * 32 + lk8];
        #pragma unroll
        for (int i = 0; i < 4; ++i)
            #pragma unroll
            for (int j = 0; j < 4; ++j)
                acc[i][j] = __builtin_amdgcn_mfma_f32_16x16x32_bf16(af[i], bfr[j], acc[i][j], 0, 0, 0);
    }

    int r0 = m0 + am + (lane >> 4) * 4;
    int c0 = n0 + bn + (lane & 15);
    #pragma unroll
    for (int j = 0; j < 4; ++j) {
        int col = c0 + j * 16;
        if (col >= Nreal) continue;
        float bs = bias[col];
        #pragma unroll
        for (int i = 0; i < 4; ++i) {
            #pragma unroll
            for (int r = 0; r < 4; ++r) {
                int rw = r0 + i * 16 + r;
                float v = acc[i][j][r] + bs;
                if (relu) v = fmaxf(v, 0.f);
                size_t o = (size_t)rw * Nstore + col;
                if (outF) outF[o] = v;
                if (outB) outB[o] = f2b(v);
            }
        }
    }
}

// ---------- persistent fused LSTM v6.2 ----------
// Same structure as v6.1 (256 blocks x 512 threads x 16 s-rows; W streamed from L2,
// 2-slot ring; S-independent counted vmcnt: kc<=1 -> 12, kc in [2,10] -> 8, kc11 -> 0).
// NEW vs v6.1: all no-reuse global traffic is NON-TEMPORAL so it stops evicting W
// from L2 (round 9 PMC: FETCH 1.65 GB/dispatch = ~13% W-miss/step = the entire
// kernel bottleneck at 1.31 TB/s achieved HBM BW):
//   - Hd / Cd / predictb stores: __builtin_nontemporal_store (written once, read
//     only by later kernels; 256 MB can't fit L2 anyway)
//   - xs A-frag loads: __builtin_nontemporal_load (each row read once by one block)
// W keeps normal caching -> ~0.77 MB resident per XCD -> misses ~ compulsory only.
__global__ __launch_bounds__(512) void lstm_k(const short* xs, const short* pW2, const float* biasP,
                                              const float* convw, const float* convb,
                                              short* Hd, short* Cd, short* predictb) {
    __shared__ alignas(16) short Wbuf[2][8][4096];   // [slot][wave][f*512 + l*8]  (128 KB)
    __shared__ alignas(16) short hfrag[4096];        // [oct 32][s 16][e 8]        (8 KB)
    __shared__ float edgeA[8][16];                   // hraw at j=32w    (per s)
    __shared__ float edgeB[8][16];                   // hraw at j=32w+31 (per s)

    const int tid = threadIdx.x;
    const int w = tid >> 6, l = tid & 63;
    const int lj = l & 15, lk = l >> 4;
    const int sb = blockIdx.x * 16;

    float biasv[8];
    #pragma unroll
    for (int f = 0; f < 8; ++f) biasv[f] = biasP[w * 128 + f * 16 + lj];
    float creg[2][4] = {};
    const float cw0 = convw[0], cw1 = convw[1], cw2 = convw[2], cb = convb[0];

    for (int i = tid; i < 4096; i += 512) hfrag[i] = 0;

    auto issueW = [&](int kc, int pp) {
        const short* src = pW2 + (((size_t)kc * 64 + w * 8) << 9) + l * 8;
        short* dst = &Wbuf[pp][w][l * 8];
        #pragma unroll
        for (int ri = 0; ri < 8; ++ri)
            __builtin_amdgcn_global_load_lds(
                (const __attribute__((address_space(1))) void*)(src + ri * 512),
                (__attribute__((address_space(3))) void*)(dst + ri * 512), 16, 0, 0);
    };

    bf16x8 ax[4];
    auto loadAx = [&](int it) {
        #pragma unroll
        for (int kc = 0; kc < 4; ++kc) {
            const short8* p = (const short8*)(xs + ((size_t)it * 4096 + sb + lj) * 128
                                              + kc * 32 + lk * 8);
            short8 v = __builtin_nontemporal_load(p);
            ax[kc] = __builtin_bit_cast(bf16x8, v);
        }
    };

    issueW(0, 0);
    issueW(1, 1);
    loadAx(0);
    __syncthreads();                // hfrag zeros visible (prologue drain is fine)

    for (int k = 0; k < 65; ++k) {
        f32x4 acc[8];
        #pragma unroll
        for (int f = 0; f < 8; ++f) acc[f] = (f32x4){biasv[f], biasv[f], biasv[f], biasv[f]};

        #pragma unroll
        for (int kc = 0; kc < 12; ++kc) {
            if (kc <= 1)       { asm volatile("s_waitcnt vmcnt(12)" ::: "memory"); }
            else if (kc == 11) { asm volatile("s_waitcnt vmcnt(0)" ::: "memory"); }
            else               { asm volatile("s_waitcnt vmcnt(8)" ::: "memory"); }
            const int p = kc & 1;
            bf16x8 af;
            if (kc < 4) af = ax[kc];
            else        af = *(const bf16x8*)&hfrag[(((kc - 4) * 4 + lk) * 16 + lj) * 8];
            #pragma unroll
            for (int f = 0; f < 8; ++f) {
                bf16x8 wf = *(const bf16x8*)&Wbuf[p][w][f * 512 + l * 8];
                acc[f] = __builtin_amdgcn_mfma_f32_16x16x32_bf16(af, wf, acc[f], 0, 0, 0);
            }
            if (kc <= 9) issueW(kc + 2, p);   // refill just-consumed slot
        }

        // ---- activations + cell update (registers) ----
        float hr[2][4];
        #pragma unroll
        for (int u = 0; u < 2; ++u)
            #pragma unroll
            for (int r = 0; r < 4; ++r) {
                float gi = acc[u][r],     gf = acc[2 + u][r];
                float gg = acc[4 + u][r], go = acc[6 + u][r];
                float c = sigf(gf) * creg[u][r] + sigf(gi) * tanhf_fast(gg);
                creg[u][r] = c;
                hr[u][r] = sigf(go) * tanhf_fast(c);
            }
        if (lj == 0) {
            #pragma unroll
            for (int r = 0; r < 4; ++r) edgeA[w][4 * lk + r] = hr[0][r];
        }
        if (lj == 15) {
            #pragma unroll
            for (int r = 0; r < 4; ++r) edgeB[w][4 * lk + r] = hr[1][r];
        }
        asm volatile("s_waitcnt lgkmcnt(0)" ::: "memory");
        __builtin_amdgcn_s_barrier();         // kc-loop hfrag reads done; edges visible

        // ---- prefetch next step FIRST (before stores -> S-independent vmcnt FIFO) ----
        if (k < 64) {
            issueW(0, 0);                      // 8 ops
            issueW(1, 1);                      // 8 ops
            loadAx((k + 1 <= 48) ? k + 1 : k); // 4 reg loads
        }

        // ---- conv over hidden dim (shuffles), h feedback + outputs (all stores nt) ----
        const int tslot = (k < 48) ? k : k - 1;
        const bool doW = (k != 48);
        const int pslot = k - 49;
        #pragma unroll
        for (int r = 0; r < 4; ++r) {
            const int s = 4 * lk + r;
            float v0 = hr[0][r], v1 = hr[1][r];
            float s0r = __shfl(v0, l + 1, 64);
            float s0l = __shfl(v0, l - 1, 64);
            float s1r = __shfl(v1, l + 1, 64);
            float s1l = __shfl(v1, l - 1, 64);
            float x01 = __shfl(v1, l - 15, 64);   // lj==15,u0: right = (u1,lj0)
            float x10 = __shfl(v0, l + 15, 64);   // lj==0, u1: left  = (u0,lj15)
            float n0r = (lj < 15) ? s0r : x01;
            float n0l = (lj > 0) ? s0l : (w > 0 ? edgeB[w - 1][s] : 0.f);
            float n1r = (lj < 15) ? s1r : (w < 7 ? edgeA[w + 1][s] : 0.f);
            float n1l = (lj > 0) ? s1l : x10;
            float h0 = cw0 * n0l + cw1 * v0 + cw2 * n0r + cb;
            float h1 = cw0 * n1l + cw1 * v1 + cw2 * n1r + cb;
            const int j0 = 32 * w + lj, j1 = j0 + 16;
            hfrag[(((j0 >> 3) * 16) + s) * 8 + (lj & 7)] = f2b(h0);
            hfrag[(((j1 >> 3) * 16) + s) * 8 + (lj & 7)] = f2b(h1);
            const int ss = sb + s;
            if (doW) {
                size_t o0 = ((size_t)ss * 64 + tslot) * 256;
                __builtin_nontemporal_store(f2b(h0), &Hd[o0 + j0]);
                __builtin_nontemporal_store(f2b(h1), &Hd[o0 + j1]);
                __builtin_nontemporal_store(f2b(creg[0][r]), &Cd[o0 + j0]);
                __builtin_nontemporal_store(f2b(creg[1][r]), &Cd[o0 + j1]);
            }
            if (pslot >= 0) {
                size_t po = ((size_t)ss * 16 + pslot) * 256;
                __builtin_nontemporal_store(f2b(h0), &predictb[po + j0]);
                __builtin_nontemporal_store(f2b(h1), &predictb[po + j1]);
            }
        }
        asm volatile("s_waitcnt lgkmcnt(0)" ::: "memory");
        __builtin_amdgcn_s_barrier();         // hfrag ready for next step (vmcnt NOT drained)
    }
    asm volatile("s_waitcnt vmcnt(0)" ::: "memory");
}

// ---------- staged bf16 [s][t][j] -> output f32 [s][j][t] transpose ----------
__global__ __launch_bounds__(256) void transpose_k(const short* Hs, const short* Cs,
                                                   float* Ho, float* Co) {
    __shared__ short tile[64][132];
    int s = blockIdx.x, jh = blockIdx.y;
    const short* src = blockIdx.z ? Cs : Hs;
    float* dst = blockIdx.z ? Co : Ho;
    #pragma unroll 4
    for (int i = 0; i < 16; ++i) {
        int idx = i * 256 + threadIdx.x;              // over 4096 short2
        int t = idx >> 6, jj2 = idx & 63;
        *(int*)&tile[t][jj2 * 2] =
            *(const int*)&src[((size_t)s * 64 + t) * 256 + jh * 128 + jj2 * 2];
    }
    __syncthreads();
    #pragma unroll 4
    for (int i = 0; i < 32; ++i) {
        int idx = i * 256 + threadIdx.x;              // over 8192
        int jj = idx >> 6, t = idx & 63;
        dst[((size_t)s * 256 + jh * 128 + jj) * 64 + t] = b2f(tile[t][jj]);
    }
}

// ---------- final: fc3 (64->1) + divide by laneC ----------
__global__ __launch_bounds__(256) void final_k(const short* t2b, const float* fW3, const float* fb3,
                                               const float* laneC, float* out0) {
    int r = blockIdx.x * 256 + threadIdx.x;
    float acc = fb3[0];
    const short* rowp = t2b + (size_t)r * 64;
    #pragma unroll 8
    for (int k = 0; k < 64; ++k) acc += b2f(rowp[k]) * fW3[k];
    out0[r] = acc / laneC[r >> 4];
}

// ---------- host ----------
extern "C" void kernel_launch(void* const* d_in, const int* in_sizes, int n_in,
                              void* d_out, int out_size, void* d_ws, size_t ws_size,
                              hipStream_t stream) {
    (void)in_sizes; (void)n_in; (void)out_size; (void)ws_size;
    const float* inputData = (const float*)d_in[0];
    const float* lane  = (const float*)d_in[1];
    const float* lgW1  = (const float*)d_in[2];  const float* lgb1 = (const float*)d_in[3];
    const float* lgW2  = (const float*)d_in[4];  const float* lgb2 = (const float*)d_in[5];
    const float* eW1   = (const float*)d_in[6];  const float* eb1  = (const float*)d_in[7];
    const float* eW2   = (const float*)d_in[8];  const float* eb2  = (const float*)d_in[9];
    const float* Wih   = (const float*)d_in[10]; const float* Whh  = (const float*)d_in[11];
    const float* bih   = (const float*)d_in[12]; const float* bhh  = (const float*)d_in[13];
    const float* convw = (const float*)d_in[14]; const float* convb= (const float*)d_in[15];
    const float* oW    = (const float*)d_in[16]; const float* ob   = (const float*)d_in[17];
    const float* fW1   = (const float*)d_in[18]; const float* fb1  = (const float*)d_in[19];
    const float* fW2   = (const float*)d_in[20]; const float* fb2  = (const float*)d_in[21];
    const float* fW3   = (const float*)d_in[22]; const float* fb3  = (const float*)d_in[23];

    float* out0 = (float*)d_out;
    float* Hout = out0 + 65536;
    float* Cout = Hout + (size_t)67108864;

    char* w = (char*)d_ws;
    size_t off = 0;
    auto alloc = [&](size_t bytes) -> void* {
        void* p = w + off;
        off += (bytes + 255) & ~(size_t)255;
        return p;
    };
    float* laneC    = (float*)alloc(4096 * 4);
    float* biasP    = (float*)alloc(1024 * 4);
    short* pW2      = (short*)alloc((size_t)1024 * 384 * 2);
    short* oWp      = (short*)alloc((size_t)128 * 256 * 2);
    short* fW1p     = (short*)alloc((size_t)256 * 128 * 2);
    short* fW2p     = (short*)alloc((size_t)128 * 256 * 2);
    short* eW2p     = (short*)alloc((size_t)128 * 64 * 2);
    short* h1       = (short*)alloc((size_t)64 * 4096 * 64 * 2);
    short* xs       = (short*)alloc((size_t)64 * 4096 * 128 * 2);
    short* predictb = (short*)alloc((size_t)65536 * 256 * 2);
    short* t0b      = (short*)alloc((size_t)65536 * 128 * 2);
    short* t1b      = (short*)alloc((size_t)65536 * 256 * 2);
    short* t2b      = (short*)alloc((size_t)65536 * 64 * 2);
    short* Hstage   = (short*)alloc((size_t)4096 * 64 * 256 * 2);
    short* Cstage   = (short*)alloc((size_t)4096 * 64 * 256 * 2);

    lanec_k<<<16, 256, 0, stream>>>(lane, lgW1, lgb1, lgW2, lgb2, laneC);
    {
        int total = 393216 + 1024 + 32768 + 32768 + 32768 + 8192;
        pack_k<<<(total + 255) / 256, 256, 0, stream>>>(Wih, Whh, bih, bhh, oW, fW1, fW2, eW2,
                                                        pW2, biasP, oWp, fW1p, fW2p, eW2p);
    }
    embed1_k<<<65536, 256, 0, stream>>>(inputData, laneC, eW1, eb1, h1);
    gemm_k<<<dim3(2048, 1), 256, 0, stream>>>(h1, 64, (const short*)nullptr, 0, eW2p, 64,
                                              eb2, (float*)nullptr, xs, 128, 128, 1);

    lstm_k<<<256, 512, 0, stream>>>(xs, pW2, biasP, convw, convb, Hstage, Cstage, predictb);

    transpose_k<<<dim3(4096, 2, 2), 256, 0, stream>>>(Hstage, Cstage, Hout, Cout);

    gemm_k<<<dim3(512, 1), 256, 0, stream>>>(predictb, 256, (const short*)nullptr, 0, oWp, 256,
                                             ob, (float*)nullptr, t0b, 128, 128, 0);
    gemm_k<<<dim3(512, 2), 256, 0, stream>>>(t0b, 128, (const short*)nullptr, 0, fW1p, 128,
                                             fb1, (float*)nullptr, t1b, 256, 256, 1);
    gemm_k<<<dim3(512, 1), 256, 0, stream>>>(t1b, 256, (const short*)nullptr, 0, fW2p, 256,
                                             fb2, (float*)nullptr, t2b, 64, 64, 1);
    final_k<<<256, 256, 0, stream>>>(t2b, fW3, fb3, laneC, out0);
}